// Round 1
// baseline (1249.583 us; speedup 1.0000x reference)
//
#include <hip/hip_runtime.h>

#define SEQ 128
#define BSZ 64
#define EMB 32
#define HD  8
#define VOC 32000
#define P   16   // positions per block in output kernel

// ---------------------------------------------------------------------------
// Kernel 1: bidirectional RNN recurrence.
// grid = 2 blocks (0=forward, 1=backward), 512 threads = 64 batch x 8 hidden.
// h-state lives in registers; cross-h exchange via __shfl within 8-lane groups.
// Writes Hcat[(s*B+b)*16 + (dir?8:0) + h].
// ---------------------------------------------------------------------------
__global__ __launch_bounds__(512) void rnn_scan_kernel(
    const int*   __restrict__ idx,
    const float* __restrict__ lookup,
    const float* __restrict__ Wxf, const float* __restrict__ Whf,
    const float* __restrict__ Wxb, const float* __restrict__ Whb,
    const float* __restrict__ Hf0, const float* __restrict__ Hb0,
    const float* __restrict__ bf1, const float* __restrict__ bf2,
    const float* __restrict__ bb1, const float* __restrict__ bb2,
    float* __restrict__ Hcat)
{
    const int dir = blockIdx.x;          // 0 = forward, 1 = backward
    const int tid = threadIdx.x;
    const int b   = tid >> 3;            // batch row 0..63
    const int h   = tid & 7;             // hidden index 0..7

    const float* Wx = dir ? Wxb : Wxf;
    const float* Wh = dir ? Whb : Whf;

    // Hoist weight columns into registers (column h of Wx / Wh).
    float wx[EMB];
#pragma unroll
    for (int e = 0; e < EMB; ++e) wx[e] = Wx[e * HD + h];
    float wh[HD];
#pragma unroll
    for (int j = 0; j < HD; ++j) wh[j] = Wh[j * HD + h];

    const float bias = dir ? (bb1[h] + bb2[h]) : (bf1[h] + bf2[h]);
    float hcur = dir ? Hb0[h] : Hf0[h];
    const int koff = dir ? HD : 0;

    for (int t = 0; t < SEQ; ++t) {
        const int s = dir ? (SEQ - 1 - t) : t;

        // lax.scan emits the PREVIOUS state: write before updating.
        Hcat[(s * BSZ + b) * 16 + koff + h] = hcur;

        // Gather embedding row for (s, b); this thread loads e = h + 8*i.
        const int ib = idx[s * BSZ + b];
        const float* xr = lookup + (size_t)ib * EMB;
        float x0 = xr[h];
        float x1 = xr[h + 8];
        float x2 = xr[h + 16];
        float x3 = xr[h + 24];

        float acc = bias;
        // x @ Wx : broadcast x[e] from lane (e&7) of this 8-lane group.
#pragma unroll
        for (int e = 0; e < EMB; ++e) {
            const int r = e >> 3;
            float src = (r == 0) ? x0 : (r == 1) ? x1 : (r == 2) ? x2 : x3;
            float xs = __shfl(src, e & 7, 8);
            acc = fmaf(xs, wx[e], acc);
        }
        // h @ Wh : broadcast previous h[j] from lane j of the group.
#pragma unroll
        for (int j = 0; j < HD; ++j) {
            float hj = __shfl(hcur, j, 8);
            acc = fmaf(hj, wh[j], acc);
        }
        hcur = tanhf(acc);
    }
}

// ---------------------------------------------------------------------------
// Kernel 2: logits = Hcat @ Wo + bo, then log_softmax over V.
// grid = 512 blocks x 256 threads; each block owns P=16 positions x all V.
// Two passes: (1) sum of exp(logit) -- max skipped, |logit| <= ~0.1 by
// construction so exp cannot overflow; (2) recompute logit, write
// logit - log(sum). Wo streamed from L2 as float4, h broadcast from LDS.
// ---------------------------------------------------------------------------
__global__ __launch_bounds__(256) void out_softmax_kernel(
    const float* __restrict__ Hcat,
    const float* __restrict__ Wo,
    const float* __restrict__ bo,
    float* __restrict__ out)
{
    __shared__ float hls[P][16];
    __shared__ float red[4][P];
    __shared__ float lsum[P];

    const int tid = threadIdx.x;
    const int pb  = blockIdx.x;

    // Load the 16 h-values for each of the P positions (exactly 256 floats).
    hls[tid >> 4][tid & 15] = Hcat[pb * (P * 16) + tid];
    __syncthreads();

    float sacc[P];
#pragma unroll
    for (int p = 0; p < P; ++p) sacc[p] = 0.f;

    // ---- pass 1: sum of exp(logit) ----
    for (int c = 0; c < 31; ++c) {
        const int v = c * 1024 + tid * 4;
        float4 bo4 = *(const float4*)(bo + v);
        float4 wo[16];
#pragma unroll
        for (int k = 0; k < 16; ++k) wo[k] = *(const float4*)(Wo + k * VOC + v);
#pragma unroll
        for (int p = 0; p < P; ++p) {
            float4 lg = bo4;
#pragma unroll
            for (int k = 0; k < 16; ++k) {
                const float hv = hls[p][k];
                lg.x = fmaf(hv, wo[k].x, lg.x);
                lg.y = fmaf(hv, wo[k].y, lg.y);
                lg.z = fmaf(hv, wo[k].z, lg.z);
                lg.w = fmaf(hv, wo[k].w, lg.w);
            }
            sacc[p] += __expf(lg.x) + __expf(lg.y) + __expf(lg.z) + __expf(lg.w);
        }
    }
    {   // remainder: v = 31744 + tid (256 values)
        const int v = 31744 + tid;
        const float bos = bo[v];
        float woS[16];
#pragma unroll
        for (int k = 0; k < 16; ++k) woS[k] = Wo[k * VOC + v];
#pragma unroll
        for (int p = 0; p < P; ++p) {
            float lg = bos;
#pragma unroll
            for (int k = 0; k < 16; ++k) lg = fmaf(hls[p][k], woS[k], lg);
            sacc[p] += __expf(lg);
        }
    }

    // ---- block reduction of sacc over 256 threads ----
    const int lane = tid & 63;
    const int wv   = tid >> 6;
#pragma unroll
    for (int p = 0; p < P; ++p) {
        float s = sacc[p];
#pragma unroll
        for (int off = 32; off > 0; off >>= 1) s += __shfl_xor(s, off, 64);
        if (lane == 0) red[wv][p] = s;
    }
    __syncthreads();
    if (tid < P) {
        lsum[tid] = logf(red[0][tid] + red[1][tid] + red[2][tid] + red[3][tid]);
    }
    __syncthreads();

    // ---- pass 2: recompute logits, write log_softmax ----
    const size_t obase = (size_t)pb * P * VOC;
    for (int c = 0; c < 31; ++c) {
        const int v = c * 1024 + tid * 4;
        float4 bo4 = *(const float4*)(bo + v);
        float4 wo[16];
#pragma unroll
        for (int k = 0; k < 16; ++k) wo[k] = *(const float4*)(Wo + k * VOC + v);
#pragma unroll
        for (int p = 0; p < P; ++p) {
            float4 lg = bo4;
#pragma unroll
            for (int k = 0; k < 16; ++k) {
                const float hv = hls[p][k];
                lg.x = fmaf(hv, wo[k].x, lg.x);
                lg.y = fmaf(hv, wo[k].y, lg.y);
                lg.z = fmaf(hv, wo[k].z, lg.z);
                lg.w = fmaf(hv, wo[k].w, lg.w);
            }
            const float ls = lsum[p];
            float4 o;
            o.x = lg.x - ls; o.y = lg.y - ls; o.z = lg.z - ls; o.w = lg.w - ls;
            *(float4*)(out + obase + (size_t)p * VOC + v) = o;
        }
    }
    {   // remainder
        const int v = 31744 + tid;
        const float bos = bo[v];
        float woS[16];
#pragma unroll
        for (int k = 0; k < 16; ++k) woS[k] = Wo[k * VOC + v];
#pragma unroll
        for (int p = 0; p < P; ++p) {
            float lg = bos;
#pragma unroll
            for (int k = 0; k < 16; ++k) lg = fmaf(hls[p][k], woS[k], lg);
            out[obase + (size_t)p * VOC + v] = lg - lsum[p];
        }
    }
}

extern "C" void kernel_launch(void* const* d_in, const int* in_sizes, int n_in,
                              void* d_out, int out_size, void* d_ws, size_t ws_size,
                              hipStream_t stream)
{
    const int*   idx    = (const int*)  d_in[0];
    const float* lookup = (const float*)d_in[1];
    const float* Wxf    = (const float*)d_in[2];
    const float* Whf    = (const float*)d_in[3];
    const float* Wxb    = (const float*)d_in[4];
    const float* Whb    = (const float*)d_in[5];
    const float* Wo     = (const float*)d_in[6];
    const float* Hf0    = (const float*)d_in[7];
    const float* Hb0    = (const float*)d_in[8];
    const float* bf1    = (const float*)d_in[9];
    const float* bf2    = (const float*)d_in[10];
    const float* bb1    = (const float*)d_in[11];
    const float* bb2    = (const float*)d_in[12];
    const float* bo     = (const float*)d_in[13];
    float* out  = (float*)d_out;
    float* Hcat = (float*)d_ws;   // 8192 x 16 floats = 512 KB

    hipLaunchKernelGGL(rnn_scan_kernel, dim3(2), dim3(512), 0, stream,
                       idx, lookup, Wxf, Whf, Wxb, Whb, Hf0, Hb0,
                       bf1, bf2, bb1, bb2, Hcat);
    hipLaunchKernelGGL(out_softmax_kernel, dim3(512), dim3(256), 0, stream,
                       Hcat, Wo, bo, out);
}